// Round 1
// baseline (84.504 us; speedup 1.0000x reference)
//
#include <hip/hip_runtime.h>

constexpr int STATE_D = 12, ACT_D = 6, IN_D = 18, W_HID = 10, N_HID = 19;
constexpr float SLOPE = 0.1f;

__device__ __forceinline__ float lrelu(float x) {
    // For 0 < slope < 1: max(x, slope*x) == leaky_relu(x)
    return fmaxf(x, SLOPE * x);
}

__global__ __launch_bounds__(256) void critic_fused(
    const float* __restrict__ state, const float* __restrict__ action,
    const float* __restrict__ W0, const float* __restrict__ b0,
    const float* __restrict__ Ws, const float* __restrict__ bs,
    const float* __restrict__ Wf, const float* __restrict__ bf,
    float* __restrict__ out, int B)
{
    const int i = blockIdx.x * blockDim.x + threadIdx.x;
    if (i >= B) return;

    float x[IN_D];
    // state row: 12 floats = 48 B, 16B-aligned for every i
    const float4* s4 = reinterpret_cast<const float4*>(state) + (size_t)i * 3;
    float4 sa = s4[0], sb = s4[1], sc = s4[2];
    x[0]=sa.x; x[1]=sa.y; x[2]=sa.z;  x[3]=sa.w;
    x[4]=sb.x; x[5]=sb.y; x[6]=sb.z;  x[7]=sb.w;
    x[8]=sc.x; x[9]=sc.y; x[10]=sc.z; x[11]=sc.w;
    // action row: 6 floats = 24 B, 8B-aligned for every i
    const float2* a2 = reinterpret_cast<const float2*>(action) + (size_t)i * 3;
    float2 aa = a2[0], ab = a2[1], ac = a2[2];
    x[12]=aa.x; x[13]=aa.y; x[14]=ab.x; x[15]=ab.y; x[16]=ac.x; x[17]=ac.y;

    float h[W_HID];
    #pragma unroll
    for (int j = 0; j < W_HID; ++j) {
        float acc = b0[j];
        #pragma unroll
        for (int k = 0; k < IN_D; ++k)
            acc = fmaf(x[k], W0[j*IN_D + k], acc);   // W0 read is wave-uniform -> s_load
        h[j] = lrelu(acc);
    }

    #pragma unroll
    for (int l = 0; l < N_HID; ++l) {
        const float* __restrict__ W  = Ws + l * W_HID * W_HID;
        const float* __restrict__ bb = bs + l * W_HID;
        float hn[W_HID];
        #pragma unroll
        for (int j = 0; j < W_HID; ++j) {
            float acc = bb[j];
            #pragma unroll
            for (int k = 0; k < W_HID; ++k)
                acc = fmaf(h[k], W[j*W_HID + k], acc);
            hn[j] = lrelu(acc);
        }
        #pragma unroll
        for (int j = 0; j < W_HID; ++j) h[j] = hn[j];
    }

    float acc = bf[0];
    #pragma unroll
    for (int k = 0; k < W_HID; ++k)
        acc = fmaf(h[k], Wf[k], acc);
    out[i] = lrelu(acc);
}

extern "C" void kernel_launch(void* const* d_in, const int* in_sizes, int n_in,
                              void* d_out, int out_size, void* d_ws, size_t ws_size,
                              hipStream_t stream) {
    const float* state  = (const float*)d_in[0];
    const float* action = (const float*)d_in[1];
    const float* W0     = (const float*)d_in[2];
    const float* b0     = (const float*)d_in[3];
    const float* Ws     = (const float*)d_in[4];
    const float* bs     = (const float*)d_in[5];
    const float* Wf     = (const float*)d_in[6];
    const float* bf     = (const float*)d_in[7];
    float* out = (float*)d_out;

    const int B = out_size;          // output is [1, B] flat
    const int block = 256;
    const int grid = (B + block - 1) / block;
    critic_fused<<<grid, block, 0, stream>>>(state, action, W0, b0, Ws, bs, Wf, bf, out, B);
}

// Round 2
// 60.049 us; speedup vs baseline: 1.4073x; 1.4073x over previous
//
#include <hip/hip_runtime.h>

typedef float v2f __attribute__((ext_vector_type(2)));

constexpr int STATE_D = 12, ACT_D = 6, IN_D = 18, W_HID = 10, N_HID = 19;
constexpr float SLOPE = 0.1f;

__device__ __forceinline__ v2f splat(float s) { v2f v; v[0] = s; v[1] = s; return v; }

__device__ __forceinline__ v2f lrelu2(v2f x) {
    // max(x, slope*x) == leaky_relu(x) for 0<slope<1 -> v_pk_mul_f32 + v_pk_max_f32
    return __builtin_elementwise_max(x, x * splat(SLOPE));
}

__global__ __launch_bounds__(256) void critic_fused_pk(
    const float* __restrict__ state, const float* __restrict__ action,
    const float* __restrict__ W0, const float* __restrict__ bias0,
    const float* __restrict__ Ws, const float* __restrict__ bs,
    const float* __restrict__ Wf, const float* __restrict__ bf,
    float* __restrict__ out, int B)
{
    const int t  = blockIdx.x * blockDim.x + threadIdx.x;
    const int i0 = t * 2;                 // this thread handles samples i0, i0+1
    if (i0 >= B) return;

    // ---- load two input rows, fully vectorized ----
    float r0[IN_D], r1[IN_D];
    {
        // state rows: 48 B each, 16B-aligned -> 6x float4 for two rows
        const float4* s4 = reinterpret_cast<const float4*>(state) + (size_t)i0 * 3;
        float4 p0 = s4[0], p1 = s4[1], p2 = s4[2];
        float4 q0 = s4[3], q1 = s4[4], q2 = s4[5];
        r0[0]=p0.x; r0[1]=p0.y; r0[2] =p0.z; r0[3] =p0.w;
        r0[4]=p1.x; r0[5]=p1.y; r0[6] =p1.z; r0[7] =p1.w;
        r0[8]=p2.x; r0[9]=p2.y; r0[10]=p2.z; r0[11]=p2.w;
        r1[0]=q0.x; r1[1]=q0.y; r1[2] =q0.z; r1[3] =q0.w;
        r1[4]=q1.x; r1[5]=q1.y; r1[6] =q1.z; r1[7] =q1.w;
        r1[8]=q2.x; r1[9]=q2.y; r1[10]=q2.z; r1[11]=q2.w;
        // action rows: 24 B each, 8B-aligned -> 6x float2 for two rows
        const float2* a2 = reinterpret_cast<const float2*>(action) + (size_t)i0 * 3;
        float2 u0 = a2[0], u1 = a2[1], u2 = a2[2];
        float2 v0 = a2[3], v1 = a2[4], v2 = a2[5];
        r0[12]=u0.x; r0[13]=u0.y; r0[14]=u1.x; r0[15]=u1.y; r0[16]=u2.x; r0[17]=u2.y;
        r1[12]=v0.x; r1[13]=v0.y; r1[14]=v1.x; r1[15]=v1.y; r1[16]=v2.x; r1[17]=v2.y;
    }

    // pack: lane-local pair (sample i0 in slot 0, i0+1 in slot 1)
    v2f x[IN_D];
    #pragma unroll
    for (int k = 0; k < IN_D; ++k) { v2f v; v[0] = r0[k]; v[1] = r1[k]; x[k] = v; }

    // ---- layer 0: 18 -> 10 ----
    v2f h[W_HID];
    #pragma unroll
    for (int j = 0; j < W_HID; ++j) {
        v2f acc = splat(bias0[j]);
        #pragma unroll
        for (int k = 0; k < IN_D; ++k)
            acc = __builtin_elementwise_fma(x[k], splat(W0[j*IN_D + k]), acc); // v_pk_fma_f32
        h[j] = lrelu2(acc);
    }

    // ---- 19 hidden layers: 10 -> 10 ----
    #pragma unroll
    for (int l = 0; l < N_HID; ++l) {
        const float* __restrict__ W  = Ws + l * W_HID * W_HID;
        const float* __restrict__ bb = bs + l * W_HID;
        v2f hn[W_HID];
        #pragma unroll
        for (int j = 0; j < W_HID; ++j) {
            v2f acc = splat(bb[j]);
            #pragma unroll
            for (int k = 0; k < W_HID; ++k)
                acc = __builtin_elementwise_fma(h[k], splat(W[j*W_HID + k]), acc);
            hn[j] = lrelu2(acc);
        }
        #pragma unroll
        for (int j = 0; j < W_HID; ++j) h[j] = hn[j];
    }

    // ---- final layer: 10 -> 1 ----
    v2f acc = splat(bf[0]);
    #pragma unroll
    for (int k = 0; k < W_HID; ++k)
        acc = __builtin_elementwise_fma(h[k], splat(Wf[k]), acc);
    acc = lrelu2(acc);

    float2 o; o.x = acc[0]; o.y = acc[1];
    reinterpret_cast<float2*>(out)[t] = o;   // 8B-aligned coalesced store
}

extern "C" void kernel_launch(void* const* d_in, const int* in_sizes, int n_in,
                              void* d_out, int out_size, void* d_ws, size_t ws_size,
                              hipStream_t stream) {
    const float* state  = (const float*)d_in[0];
    const float* action = (const float*)d_in[1];
    const float* W0     = (const float*)d_in[2];
    const float* b0     = (const float*)d_in[3];
    const float* Ws     = (const float*)d_in[4];
    const float* bs     = (const float*)d_in[5];
    const float* Wf     = (const float*)d_in[6];
    const float* bf     = (const float*)d_in[7];
    float* out = (float*)d_out;

    const int B = out_size;                  // [1, B] flat; B is even (1048576)
    const int nthreads = B / 2;              // 2 samples per thread
    const int block = 256;
    const int grid = (nthreads + block - 1) / block;
    critic_fused_pk<<<grid, block, 0, stream>>>(state, action, W0, b0, Ws, bs, Wf, bf, out, B);
}

// Round 3
// 54.139 us; speedup vs baseline: 1.5609x; 1.1092x over previous
//
#include <hip/hip_runtime.h>

typedef float v2f __attribute__((ext_vector_type(2)));

constexpr int IN_D = 18, W_HID = 10, N_HID = 19;
constexpr float SLOPE = 0.1f;

__device__ __forceinline__ v2f splat(float s) { v2f v; v[0] = s; v[1] = s; return v; }

__device__ __forceinline__ v2f lrelu2(v2f x) {
    // max(x, slope*x) == leaky_relu(x) for 0<slope<1 -> v_pk_mul_f32 + v_pk_max_f32
    return __builtin_elementwise_max(x, x * splat(SLOPE));
}

// 4 samples per thread: two independent packed-fp32 chains (a: samples 0,1; b: samples 2,3).
__global__ __launch_bounds__(256) void critic_fused_pk4(
    const float* __restrict__ state, const float* __restrict__ action,
    const float* __restrict__ W0, const float* __restrict__ bias0,
    const float* __restrict__ Ws, const float* __restrict__ bs,
    const float* __restrict__ Wf, const float* __restrict__ bf,
    float* __restrict__ out, int B)
{
    const int t = blockIdx.x * blockDim.x + threadIdx.x;
    if (t * 4 >= B) return;

    // ---- load 4 state rows (4 x 48 B = 192 B, 16B-aligned) as 12x float4 ----
    float Sf[48];
    {
        const float4* s4 = reinterpret_cast<const float4*>(state) + (size_t)t * 12;
        #pragma unroll
        for (int r = 0; r < 12; ++r) {
            float4 v = s4[r];
            Sf[4*r] = v.x; Sf[4*r+1] = v.y; Sf[4*r+2] = v.z; Sf[4*r+3] = v.w;
        }
    }
    // ---- load 4 action rows (4 x 24 B = 96 B, 16B-aligned) as 6x float4 ----
    float Af[24];
    {
        const float4* a4 = reinterpret_cast<const float4*>(action) + (size_t)t * 6;
        #pragma unroll
        for (int r = 0; r < 6; ++r) {
            float4 v = a4[r];
            Af[4*r] = v.x; Af[4*r+1] = v.y; Af[4*r+2] = v.z; Af[4*r+3] = v.w;
        }
    }

    // pack inputs: xa = {sample0, sample1}, xb = {sample2, sample3}
    v2f xa[IN_D], xb[IN_D];
    #pragma unroll
    for (int k = 0; k < 12; ++k) {
        v2f a; a[0] = Sf[k];      a[1] = Sf[12 + k]; xa[k] = a;
        v2f b; b[0] = Sf[24 + k]; b[1] = Sf[36 + k]; xb[k] = b;
    }
    #pragma unroll
    for (int k = 0; k < 6; ++k) {
        v2f a; a[0] = Af[k];      a[1] = Af[6 + k];  xa[12 + k] = a;
        v2f b; b[0] = Af[12 + k]; b[1] = Af[18 + k]; xb[12 + k] = b;
    }

    // ---- layer 0: 18 -> 10 ----
    v2f ha[W_HID], hb[W_HID];
    #pragma unroll
    for (int j = 0; j < W_HID; ++j) {
        v2f aa = splat(bias0[j]);
        v2f ab = aa;
        #pragma unroll
        for (int k = 0; k < IN_D; ++k) {
            v2f w = splat(W0[j*IN_D + k]);
            aa = __builtin_elementwise_fma(xa[k], w, aa);
            ab = __builtin_elementwise_fma(xb[k], w, ab);
        }
        ha[j] = lrelu2(aa);
        hb[j] = lrelu2(ab);
    }

    // ---- 19 hidden layers: 10 -> 10 ----
    #pragma unroll
    for (int l = 0; l < N_HID; ++l) {
        const float* __restrict__ W  = Ws + l * W_HID * W_HID;
        const float* __restrict__ bb = bs + l * W_HID;
        v2f na[W_HID], nb[W_HID];
        #pragma unroll
        for (int j = 0; j < W_HID; ++j) {
            v2f aa = splat(bb[j]);
            v2f ab = aa;
            #pragma unroll
            for (int k = 0; k < W_HID; ++k) {
                v2f w = splat(W[j*W_HID + k]);
                aa = __builtin_elementwise_fma(ha[k], w, aa);
                ab = __builtin_elementwise_fma(hb[k], w, ab);
            }
            na[j] = lrelu2(aa);
            nb[j] = lrelu2(ab);
        }
        #pragma unroll
        for (int j = 0; j < W_HID; ++j) { ha[j] = na[j]; hb[j] = nb[j]; }
    }

    // ---- final layer: 10 -> 1 ----
    v2f aa = splat(bf[0]);
    v2f ab = aa;
    #pragma unroll
    for (int k = 0; k < W_HID; ++k) {
        v2f w = splat(Wf[k]);
        aa = __builtin_elementwise_fma(ha[k], w, aa);
        ab = __builtin_elementwise_fma(hb[k], w, ab);
    }
    aa = lrelu2(aa);
    ab = lrelu2(ab);

    float4 o; o.x = aa[0]; o.y = aa[1]; o.z = ab[0]; o.w = ab[1];
    reinterpret_cast<float4*>(out)[t] = o;   // 16B-aligned coalesced store
}

extern "C" void kernel_launch(void* const* d_in, const int* in_sizes, int n_in,
                              void* d_out, int out_size, void* d_ws, size_t ws_size,
                              hipStream_t stream) {
    const float* state  = (const float*)d_in[0];
    const float* action = (const float*)d_in[1];
    const float* W0     = (const float*)d_in[2];
    const float* b0     = (const float*)d_in[3];
    const float* Ws     = (const float*)d_in[4];
    const float* bs     = (const float*)d_in[5];
    const float* Wf     = (const float*)d_in[6];
    const float* bf     = (const float*)d_in[7];
    float* out = (float*)d_out;

    const int B = out_size;                  // [1, B] flat; B = 1048576 (div by 4)
    const int nthreads = B / 4;              // 4 samples per thread
    const int block = 256;
    const int grid = (nthreads + block - 1) / block;
    critic_fused_pk4<<<grid, block, 0, stream>>>(state, action, W0, b0, Ws, bs, Wf, bf, out, B);
}